// Round 1
// baseline (176.619 us; speedup 1.0000x reference)
//
#include <hip/hip_runtime.h>
#include <hip/hip_bf16.h>

typedef __bf16 bf16x8 __attribute__((ext_vector_type(8)));
typedef float  f32x4  __attribute__((ext_vector_type(4)));

// ---------------------------------------------------------------------------
// Stage 1: qkv = kern_tok @ qkv_w + qkv_b ; split into q(scaled),k,v
// ---------------------------------------------------------------------------
__global__ __launch_bounds__(192) void qkv_kernel(
    const float* __restrict__ conv_w, const float* __restrict__ qkv_w,
    const float* __restrict__ qkv_b,
    float* __restrict__ qv, float* __restrict__ kvv, float* __restrict__ vv)
{
    __shared__ float tok[64];
    const int bid = blockIdx.x;          // co*36 + s
    const int co = bid / 36, s = bid - co * 36;
    const int w = s / 9, p = s - w * 9;
    const int t = threadIdx.x;           // 192
    if (t < 64) tok[t] = conv_w[(((w * 64 + co) * 64 + t) * 9) + p];
    __syncthreads();
    float acc = qkv_b[t];
#pragma unroll 8
    for (int ci = 0; ci < 64; ++ci) acc += tok[ci] * qkv_w[ci * 192 + t];
    const int trip = t >> 6, rem = t & 63, h = rem >> 3, d = rem & 7;
    if (trip == 0) acc *= 0.35355339059327373f;   // hd^-0.5, hd=8
    float* dst = (trip == 0) ? qv : ((trip == 1) ? kvv : vv);
    dst[((co * 8 + h) * 36 + s) * 8 + d] = acc;
}

// ---------------------------------------------------------------------------
// Stage 2: attention per (co, head): softmax(q k^T) v  -> ao[co][s][h*8+d]
// ---------------------------------------------------------------------------
__global__ __launch_bounds__(64) void attn_kernel(
    const float* __restrict__ qv, const float* __restrict__ kvv,
    const float* __restrict__ vv, float* __restrict__ ao)
{
    __shared__ float kl[288], vl[288];
    const int bid = blockIdx.x;          // co*8 + h
    const int t = threadIdx.x;           // 64
    const float* kb = kvv + bid * 288;
    const float* vb = vv + bid * 288;
    for (int i = t; i < 288; i += 64) { kl[i] = kb[i]; vl[i] = vb[i]; }
    __syncthreads();
    if (t < 36) {
        float q[8];
        const float* qb = qv + bid * 288 + t * 8;
#pragma unroll
        for (int d = 0; d < 8; ++d) q[d] = qb[d];
        float sc[36];
        float mx = -1e30f;
#pragma unroll
        for (int u = 0; u < 36; ++u) {
            float a = 0.f;
#pragma unroll
            for (int d = 0; d < 8; ++d) a += q[d] * kl[u * 8 + d];
            sc[u] = a;
            mx = fmaxf(mx, a);
        }
        float sum = 0.f;
        float o[8] = {0.f,0.f,0.f,0.f,0.f,0.f,0.f,0.f};
#pragma unroll
        for (int u = 0; u < 36; ++u) {
            float e = expf(sc[u] - mx);
            sum += e;
#pragma unroll
            for (int d = 0; d < 8; ++d) o[d] += e * vl[u * 8 + d];
        }
        const float inv = 1.0f / sum;
        const int co = bid >> 3, h = bid & 7;
        float* dst = ao + (co * 36 + t) * 64 + h * 8;
#pragma unroll
        for (int d = 0; d < 8; ++d) dst[d] = o[d] * inv;
    }
}

// ---------------------------------------------------------------------------
// Stage 3: proj + SE + write bf16 kernels  kout[(w*9+p)*64 + co]*64 + ci
// ---------------------------------------------------------------------------
__global__ __launch_bounds__(64) void proj_se_kernel(
    const float* __restrict__ ao, const float* __restrict__ proj_w,
    const float* __restrict__ proj_b,
    const float* __restrict__ se_w1, const float* __restrict__ se_b1,
    const float* __restrict__ se_w2, const float* __restrict__ se_b2,
    ushort* __restrict__ kout)
{
    __shared__ float al[9][64];
    __shared__ float pool[64];
    __shared__ float hb[4];
    const int bid = blockIdx.x;          // w*64 + co
    const int w = bid >> 6, co = bid & 63;
    const int t = threadIdx.x;           // 64 (= ci)
    for (int i = t; i < 576; i += 64) {
        int p = i >> 6, j = i & 63;
        al[p][j] = ao[(co * 36 + w * 9 + p) * 64 + j];
    }
    __syncthreads();
    float kv[9];
#pragma unroll
    for (int p = 0; p < 9; ++p) {
        float a = proj_b[t];
#pragma unroll 8
        for (int j = 0; j < 64; ++j) a += al[p][j] * proj_w[j * 64 + t];
        kv[p] = a;
    }
    float pl = 0.f;
#pragma unroll
    for (int p = 0; p < 9; ++p) pl += kv[p];
    pool[t] = pl * (1.0f / 9.0f);
    __syncthreads();
    if (t < 4) {
        float hh = se_b1[w * 4 + t];
#pragma unroll 8
        for (int c = 0; c < 64; ++c) hh += pool[c] * se_w1[(w * 4 + t) * 64 + c];
        hb[t] = fmaxf(hh, 0.0f);
    }
    __syncthreads();
    float z = se_b2[w * 64 + t];
#pragma unroll
    for (int d = 0; d < 4; ++d) z += hb[d] * se_w2[(w * 64 + t) * 4 + d];
    const float sg = 1.0f / (1.0f + expf(-z));
#pragma unroll
    for (int p = 0; p < 9; ++p) {
        __hip_bfloat16 hv = __float2bfloat16(kv[p] * sg);
        kout[((w * 9 + p) * 64 + co) * 64 + t] = *(const ushort*)&hv;
    }
}

// ---------------------------------------------------------------------------
// Stage 4: dynamic per-window 3x3 conv, implicit GEMM, bf16 MFMA.
// Tile: 16x16 output px (M=256), N=64 co, K = 9 taps x 64 ci.
// 256 thr = 4 waves; wave wv: spatial rows 4wv..4wv+3 (M=64), all 64 co.
//
// vs previous version:
//  - kern is NOT staged in LDS. Each lane's B fragment is a contiguous 16B
//    slice of kout (288 KB total -> permanently L2-resident); loaded straight
//    from global with a 2-deep register prefetch across taps. This removes
//    the 16 KB kern double-buffer AND all 9 per-tap barriers: only ONE
//    __syncthreads in the kernel (after input staging), so waves drift and
//    hide each other's latency.
//  - LDS 57856 -> 41472 B => 3 blocks/CU (12 waves) instead of 2 (8 waves).
//    __launch_bounds__(256,3) caps VGPR at ~170 (acc 64 + B dbuf 64 + misc).
//  - MFMA operands swapped: mfma(Bf, Af) so D's reg axis runs over
//    consecutive co -> epilogue is 16x global_store_dwordx4 per thread
//    instead of 64 scalar stores.
// ---------------------------------------------------------------------------
__global__ __launch_bounds__(256, 3) void conv_kernel(
    const float* __restrict__ x, const ushort* __restrict__ kern,
    float* __restrict__ out)
{
    __shared__ alignas(16) ushort in_lds[18 * 18 * 64];   // 41472 B

    const int tid = threadIdx.x;
    const int bz = blockIdx.z;
    const int w = bz >> 3, b = bz & 7;
    const int gi = w >> 1, gj = w & 1;
    const int i0 = blockIdx.y * 16, j0 = blockIdx.x * 16;

    // ---- stage input tile (18x18 px, 64 ch, fp32->bf16, zero halo)
    {
        const int cc = (tid & 15) * 4;
        for (int pp = tid >> 4; pp < 324; pp += 16) {
            int r = pp / 18;
            int q = pp - r * 18;
            int iy = i0 - 1 + r, jx = j0 - 1 + q;
            float4 v = make_float4(0.f, 0.f, 0.f, 0.f);
            if (iy >= 0 && iy < 128 && jx >= 0 && jx < 128) {
                size_t xi = (((size_t)b * 65536u) +
                             (size_t)(gi * 128 + iy) * 256 + (size_t)(gj * 128 + jx)) * 64 + cc;
                v = *(const float4*)(x + xi);
            }
            union { ushort4 u; ushort h[4]; } tmp;
            __hip_bfloat16 b0 = __float2bfloat16(v.x); tmp.h[0] = *(const ushort*)&b0;
            __hip_bfloat16 b1 = __float2bfloat16(v.y); tmp.h[1] = *(const ushort*)&b1;
            __hip_bfloat16 b2 = __float2bfloat16(v.z); tmp.h[2] = *(const ushort*)&b2;
            __hip_bfloat16 b3 = __float2bfloat16(v.w); tmp.h[3] = *(const ushort*)&b3;
            *(ushort4*)((char*)in_lds + (((r * 18 + q) << 7) + ((cc * 2) ^ ((q & 7) << 4)))) = tmp.u;
        }
    }
    __syncthreads();

    const int wv   = tid >> 6;
    const int lane = tid & 63;
    const int l15  = lane & 15;
    const int hi4  = lane >> 4;        // 0..3

    f32x4 acc[4][4];
#pragma unroll
    for (int mf = 0; mf < 4; ++mf)
#pragma unroll
        for (int nf = 0; nf < 4; ++nf)
            acc[mf][nf] = (f32x4){0.f, 0.f, 0.f, 0.f};

    // Per-lane B-fragment base: kern[(w*9+p)*4096 + co*64 + ci0], co = nf*16+l15,
    // ci0 = ks*32 + hi4*8  -> contiguous 16 B per (nf,ks). L2-resident.
    const ushort* kb = kern + (size_t)(w * 9) * 4096 + l15 * 64 + hi4 * 8;

    bf16x8 Bcur[4][2];
#pragma unroll
    for (int nf = 0; nf < 4; ++nf)
#pragma unroll
        for (int ks = 0; ks < 2; ++ks)
            Bcur[nf][ks] = *(const bf16x8*)(kb + nf * 1024 + ks * 32);

#pragma unroll
    for (int p = 0; p < 9; ++p) {
        // ---- prefetch next tap's B fragments into registers (L2 hit)
        bf16x8 Bnext[4][2];
        if (p < 8) {
            const ushort* kn = kb + (p + 1) * 4096;
#pragma unroll
            for (int nf = 0; nf < 4; ++nf)
#pragma unroll
                for (int ks = 0; ks < 2; ++ks)
                    Bnext[nf][ks] = *(const bf16x8*)(kn + nf * 1024 + ks * 32);
        }

        const int kh = p / 3, kw = p - kh * 3;
        const int q = l15 + kw;
        const int swz = (q & 7) << 4;
#pragma unroll
        for (int mf = 0; mf < 4; ++mf) {
            const int r = wv * 4 + mf + kh;
            const int rowbase = (r * 18 + q) << 7;
#pragma unroll
            for (int ks = 0; ks < 2; ++ks) {
                int c2 = (ks << 6) | (hi4 << 4);
                bf16x8 Af = *(const bf16x8*)((const char*)in_lds + (rowbase + (c2 ^ swz)));
#pragma unroll
                for (int nf = 0; nf < 4; ++nf)
                    acc[mf][nf] = __builtin_amdgcn_mfma_f32_16x16x32_bf16(
                        Bcur[nf][ks], Af, acc[mf][nf], 0, 0, 0);
            }
        }

        if (p < 8) {
#pragma unroll
            for (int nf = 0; nf < 4; ++nf)
#pragma unroll
                for (int ks = 0; ks < 2; ++ks)
                    Bcur[nf][ks] = Bnext[nf][ks];
        }
    }

    // ---- epilogue (swapped D layout): col(l15) = px j, row(hi4*4+reg) = co.
    // acc[mf][nf][reg] -> out[(rowoff + l15)*64 + nf*16 + hi4*4 + reg]
    // 4 consecutive co per lane => float4 stores.
#pragma unroll
    for (int mf = 0; mf < 4; ++mf) {
        const int iloc = wv * 4 + mf;
        const size_t rowoff = ((size_t)b * 65536u) +
                              (size_t)(gi * 128 + i0 + iloc) * 256 + (size_t)(gj * 128 + j0);
#pragma unroll
        for (int nf = 0; nf < 4; ++nf) {
            *(f32x4*)(out + (rowoff + l15) * 64 + nf * 16 + hi4 * 4) = acc[mf][nf];
        }
    }
}

// ---------------------------------------------------------------------------
extern "C" void kernel_launch(void* const* d_in, const int* in_sizes, int n_in,
                              void* d_out, int out_size, void* d_ws, size_t ws_size,
                              hipStream_t stream)
{
    const float* x      = (const float*)d_in[0];
    const float* conv_w = (const float*)d_in[1];
    const float* qkv_w  = (const float*)d_in[2];
    const float* qkv_b  = (const float*)d_in[3];
    const float* proj_w = (const float*)d_in[4];
    const float* proj_b = (const float*)d_in[5];
    const float* se_w1  = (const float*)d_in[6];
    const float* se_b1  = (const float*)d_in[7];
    const float* se_w2  = (const float*)d_in[8];
    const float* se_b2  = (const float*)d_in[9];
    float* out = (float*)d_out;

    float* qv = (float*)d_ws;            // 147456 f
    float* kv = qv + 147456;             // 147456 f
    float* vv = kv + 147456;             // 147456 f
    float* ao = vv + 147456;             // 147456 f
    ushort* kb = (ushort*)(ao + 147456); // 147456 u16  (total ~2.6 MB)

    hipLaunchKernelGGL(qkv_kernel, dim3(2304), dim3(192), 0, stream,
                       conv_w, qkv_w, qkv_b, qv, kv, vv);
    hipLaunchKernelGGL(attn_kernel, dim3(512), dim3(64), 0, stream, qv, kv, vv, ao);
    hipLaunchKernelGGL(proj_se_kernel, dim3(256), dim3(64), 0, stream,
                       ao, proj_w, proj_b, se_w1, se_b1, se_w2, se_b2, kb);
    hipLaunchKernelGGL(conv_kernel, dim3(8, 8, 32), dim3(256), 0, stream, x, kb, out);
}

// Round 2
// 170.091 us; speedup vs baseline: 1.0384x; 1.0384x over previous
//
#include <hip/hip_runtime.h>
#include <hip/hip_bf16.h>

typedef __bf16 bf16x8 __attribute__((ext_vector_type(8)));
typedef float  f32x4  __attribute__((ext_vector_type(4)));

// ---------------------------------------------------------------------------
// Stage 1: qkv = kern_tok @ qkv_w + qkv_b ; split into q(scaled),k,v
// ---------------------------------------------------------------------------
__global__ __launch_bounds__(192) void qkv_kernel(
    const float* __restrict__ conv_w, const float* __restrict__ qkv_w,
    const float* __restrict__ qkv_b,
    float* __restrict__ qv, float* __restrict__ kvv, float* __restrict__ vv)
{
    __shared__ float tok[64];
    const int bid = blockIdx.x;          // co*36 + s
    const int co = bid / 36, s = bid - co * 36;
    const int w = s / 9, p = s - w * 9;
    const int t = threadIdx.x;           // 192
    if (t < 64) tok[t] = conv_w[(((w * 64 + co) * 64 + t) * 9) + p];
    __syncthreads();
    float acc = qkv_b[t];
#pragma unroll 8
    for (int ci = 0; ci < 64; ++ci) acc += tok[ci] * qkv_w[ci * 192 + t];
    const int trip = t >> 6, rem = t & 63, h = rem >> 3, d = rem & 7;
    if (trip == 0) acc *= 0.35355339059327373f;   // hd^-0.5, hd=8
    float* dst = (trip == 0) ? qv : ((trip == 1) ? kvv : vv);
    dst[((co * 8 + h) * 36 + s) * 8 + d] = acc;
}

// ---------------------------------------------------------------------------
// Stage 2: attention per (co, head): softmax(q k^T) v  -> ao[co][s][h*8+d]
// ---------------------------------------------------------------------------
__global__ __launch_bounds__(64) void attn_kernel(
    const float* __restrict__ qv, const float* __restrict__ kvv,
    const float* __restrict__ vv, float* __restrict__ ao)
{
    __shared__ float kl[288], vl[288];
    const int bid = blockIdx.x;          // co*8 + h
    const int t = threadIdx.x;           // 64
    const float* kb = kvv + bid * 288;
    const float* vb = vv + bid * 288;
    for (int i = t; i < 288; i += 64) { kl[i] = kb[i]; vl[i] = vb[i]; }
    __syncthreads();
    if (t < 36) {
        float q[8];
        const float* qb = qv + bid * 288 + t * 8;
#pragma unroll
        for (int d = 0; d < 8; ++d) q[d] = qb[d];
        float sc[36];
        float mx = -1e30f;
#pragma unroll
        for (int u = 0; u < 36; ++u) {
            float a = 0.f;
#pragma unroll
            for (int d = 0; d < 8; ++d) a += q[d] * kl[u * 8 + d];
            sc[u] = a;
            mx = fmaxf(mx, a);
        }
        float sum = 0.f;
        float o[8] = {0.f,0.f,0.f,0.f,0.f,0.f,0.f,0.f};
#pragma unroll
        for (int u = 0; u < 36; ++u) {
            float e = expf(sc[u] - mx);
            sum += e;
#pragma unroll
            for (int d = 0; d < 8; ++d) o[d] += e * vl[u * 8 + d];
        }
        const float inv = 1.0f / sum;
        const int co = bid >> 3, h = bid & 7;
        float* dst = ao + (co * 36 + t) * 64 + h * 8;
#pragma unroll
        for (int d = 0; d < 8; ++d) dst[d] = o[d] * inv;
    }
}

// ---------------------------------------------------------------------------
// Stage 3: proj + SE + write bf16 kernels.
// NEW kout layout: [(w*9+p)*2 + ci_half][co][ci32]  (4 KB contiguous chunks,
// so conv can stage each (tap, ci-half) with global_load_lds).
// ---------------------------------------------------------------------------
__global__ __launch_bounds__(64) void proj_se_kernel(
    const float* __restrict__ ao, const float* __restrict__ proj_w,
    const float* __restrict__ proj_b,
    const float* __restrict__ se_w1, const float* __restrict__ se_b1,
    const float* __restrict__ se_w2, const float* __restrict__ se_b2,
    ushort* __restrict__ kout)
{
    __shared__ float al[9][64];
    __shared__ float pool[64];
    __shared__ float hb[4];
    const int bid = blockIdx.x;          // w*64 + co
    const int w = bid >> 6, co = bid & 63;
    const int t = threadIdx.x;           // 64 (= ci)
    for (int i = t; i < 576; i += 64) {
        int p = i >> 6, j = i & 63;
        al[p][j] = ao[(co * 36 + w * 9 + p) * 64 + j];
    }
    __syncthreads();
    float kv[9];
#pragma unroll
    for (int p = 0; p < 9; ++p) {
        float a = proj_b[t];
#pragma unroll 8
        for (int j = 0; j < 64; ++j) a += al[p][j] * proj_w[j * 64 + t];
        kv[p] = a;
    }
    float pl = 0.f;
#pragma unroll
    for (int p = 0; p < 9; ++p) pl += kv[p];
    pool[t] = pl * (1.0f / 9.0f);
    __syncthreads();
    if (t < 4) {
        float hh = se_b1[w * 4 + t];
#pragma unroll 8
        for (int c = 0; c < 64; ++c) hh += pool[c] * se_w1[(w * 4 + t) * 64 + c];
        hb[t] = fmaxf(hh, 0.0f);
    }
    __syncthreads();
    float z = se_b2[w * 64 + t];
#pragma unroll
    for (int d = 0; d < 4; ++d) z += hb[d] * se_w2[(w * 64 + t) * 4 + d];
    const float sg = 1.0f / (1.0f + expf(-z));
    const int hhalf = t >> 5, ci32 = t & 31;
#pragma unroll
    for (int p = 0; p < 9; ++p) {
        __hip_bfloat16 hv = __float2bfloat16(kv[p] * sg);
        kout[((w * 9 + p) * 2 + hhalf) * 2048 + co * 32 + ci32] = *(const ushort*)&hv;
    }
}

// ---------------------------------------------------------------------------
// Stage 4: dynamic per-window 3x3 conv, implicit GEMM, bf16 MFMA.
// Tile: 16x16 output px (M-free dim), N=64 co, K = 9 taps x 64 ci,
// processed as 18 steps of K=32 (ci split in two halves).
//
// Occupancy/concurrency redesign vs round 1 (which regressed):
//  - ci-split: input tile 18x18x32 bf16 = 20736 B, kern dbuf 2x4096 B
//    -> LDS 28928 B -> 4 blocks/CU with __launch_bounds__(256,4): 16 waves/CU
//    (round 0: 8). 64 B/px rows make all ds_reads contiguous-1024B,
//    conflict-free with NO swizzle.
//  - Input staging is the real bottleneck (Little's law: ~1 load in flight
//    per wave ~= 2 TB/s chip ceiling, matching measured 1.7-1.8 TB/s).
//    Staging now batches 4 independent float4 loads into regs before the
//    cvt+ds_write pass -> 4x in-flight bytes per wave, x2 waves/CU.
//  - kern staged with global_load_lds (16 B, linear dest) one step ahead
//    into buf^1: true double-buffer with zero VGPR cost; the compiler's
//    vmcnt-drain before __syncthreads provides the completion wait.
//  - Epilogue kept from round 1: swapped mfma(K,A) so D reg axis = 4
//    consecutive co -> f32x4 stores.
// ---------------------------------------------------------------------------
__global__ __launch_bounds__(256, 4) void conv_kernel(
    const float* __restrict__ x, const ushort* __restrict__ kern,
    float* __restrict__ out)
{
    __shared__ alignas(16) ushort in_lds[18 * 18 * 32];   // 20736 B
    __shared__ alignas(16) ushort kn_lds[2 * 2048];       // 8192 B (2 x 4KB)

    const int tid = threadIdx.x;
    const int bz = blockIdx.z;
    const int w = bz >> 3, b = bz & 7;
    const int gi = w >> 1, gj = w & 1;
    const int i0 = blockIdx.y * 16, j0 = blockIdx.x * 16;

    const int wv   = tid >> 6;
    const int lane = tid & 63;
    const int l15  = lane & 15;
    const int hi4  = lane >> 4;        // 0..3

    // kern chunks for this window: [p*2+h][co][ci32], 2048 ushorts each
    const ushort* kbase = kern + (size_t)w * 36864;

    // ---- async kern stage: wave wv loads its 1024 B of the 4 KB chunk,
    // linear LDS dest (global_load_lds: uniform base + lane*16)
    auto stage_kern = [&](int chunk_ush, int buf) {
        const ushort* gsrc = kbase + chunk_ush + (wv << 9) + (lane << 3);
        __builtin_amdgcn_global_load_lds(
            (const __attribute__((address_space(1))) unsigned int*)gsrc,
            (__attribute__((address_space(3))) unsigned int*)
                ((char*)kn_lds + (buf << 12) + (wv << 10)),
            16, 0, 0);
    };

    // ---- input staging, one ci-half: 18x18 px, 32 ch, fp32->bf16.
    // 8 threads/px (4 ch each); batched: 4 loads in flight, then cvt+write.
    auto stage_input = [&](int h) {
        const int cc = (tid & 7) << 2;     // 0..28 (channel within half)
        const int p0 = tid >> 3;           // 0..31
        for (int base = 0; base < 324; base += 128) {
            float4 vb[4];
#pragma unroll
            for (int k2 = 0; k2 < 4; ++k2) {
                const int pp = p0 + base + (k2 << 5);
                float4 v = make_float4(0.f, 0.f, 0.f, 0.f);
                if (pp < 324) {
                    const int r = pp / 18, q = pp - r * 18;
                    const int iy = i0 - 1 + r, jx = j0 - 1 + q;
                    if (iy >= 0 && iy < 128 && jx >= 0 && jx < 128) {
                        const size_t xi =
                            (((size_t)b << 16) +
                             (size_t)(gi * 128 + iy) * 256 + (size_t)(gj * 128 + jx)) * 64 +
                            h * 32 + cc;
                        v = *(const float4*)(x + xi);
                    }
                }
                vb[k2] = v;
            }
#pragma unroll
            for (int k2 = 0; k2 < 4; ++k2) {
                const int pp = p0 + base + (k2 << 5);
                if (pp < 324) {
                    union { ushort4 u; ushort h4[4]; } tmp;
                    __hip_bfloat16 b0 = __float2bfloat16(vb[k2].x); tmp.h4[0] = *(const ushort*)&b0;
                    __hip_bfloat16 b1 = __float2bfloat16(vb[k2].y); tmp.h4[1] = *(const ushort*)&b1;
                    __hip_bfloat16 b2 = __float2bfloat16(vb[k2].z); tmp.h4[2] = *(const ushort*)&b2;
                    __hip_bfloat16 b3 = __float2bfloat16(vb[k2].w); tmp.h4[3] = *(const ushort*)&b3;
                    *(ushort4*)((char*)in_lds + ((pp << 6) + (cc << 1))) = tmp.u;
                }
            }
        }
    };

    f32x4 acc[4][4];
#pragma unroll
    for (int mf = 0; mf < 4; ++mf)
#pragma unroll
        for (int nf = 0; nf < 4; ++nf)
            acc[mf][nf] = (f32x4){0.f, 0.f, 0.f, 0.f};

    // ---- prologue: kern step 0 (p=0,h=0 -> chunk 0) async + input half 0
    stage_kern(0, 0);
    stage_input(0);
    __syncthreads();     // drains both lgkmcnt (ds_writes) and vmcnt (gll)

#pragma unroll
    for (int step = 0; step < 18; ++step) {
        const int buf = step & 1;
        const int h = step / 9, p = step - h * 9;

        // issue next step's kern chunk into the other buffer (async)
        if (step < 17) {
            const int s1 = step + 1;
            const int h1 = s1 / 9, p1 = s1 - h1 * 9;
            stage_kern((p1 * 2 + h1) * 2048, buf ^ 1);
        }

        // kern fragments: co = nf*16+l15 (M), k = hi4*8.. (ci within half)
        bf16x8 Kf[4];
#pragma unroll
        for (int nf = 0; nf < 4; ++nf)
            Kf[nf] = *(const bf16x8*)((const char*)kn_lds +
                      ((buf << 12) + ((nf * 16 + l15) << 6) + (hi4 << 4)));

        const int kh = p / 3, kw = p - kh * 3;
        const int q = l15 + kw;
#pragma unroll
        for (int mf = 0; mf < 4; ++mf) {
            const int r = wv * 4 + mf + kh;
            bf16x8 Af = *(const bf16x8*)((const char*)in_lds +
                          (((r * 18 + q) << 6) + (hi4 << 4)));
#pragma unroll
            for (int nf = 0; nf < 4; ++nf)
                acc[mf][nf] = __builtin_amdgcn_mfma_f32_16x16x32_bf16(
                    Kf[nf], Af, acc[mf][nf], 0, 0, 0);
        }

        if (step == 8) {
            // all waves done reading half-0 input; restage with half 1
            __syncthreads();
            stage_input(1);
        }
        __syncthreads();
    }

    // ---- epilogue: D col(l15) = px j, row(hi4*4+reg) = co (4 consecutive)
#pragma unroll
    for (int mf = 0; mf < 4; ++mf) {
        const int iloc = wv * 4 + mf;
        const size_t rowoff = ((size_t)b << 16) +
                              (size_t)(gi * 128 + i0 + iloc) * 256 + (size_t)(gj * 128 + j0);
#pragma unroll
        for (int nf = 0; nf < 4; ++nf) {
            *(f32x4*)(out + (rowoff + l15) * 64 + nf * 16 + hi4 * 4) = acc[mf][nf];
        }
    }
}

// ---------------------------------------------------------------------------
extern "C" void kernel_launch(void* const* d_in, const int* in_sizes, int n_in,
                              void* d_out, int out_size, void* d_ws, size_t ws_size,
                              hipStream_t stream)
{
    const float* x      = (const float*)d_in[0];
    const float* conv_w = (const float*)d_in[1];
    const float* qkv_w  = (const float*)d_in[2];
    const float* qkv_b  = (const float*)d_in[3];
    const float* proj_w = (const float*)d_in[4];
    const float* proj_b = (const float*)d_in[5];
    const float* se_w1  = (const float*)d_in[6];
    const float* se_b1  = (const float*)d_in[7];
    const float* se_w2  = (const float*)d_in[8];
    const float* se_b2  = (const float*)d_in[9];
    float* out = (float*)d_out;

    float* qv = (float*)d_ws;            // 147456 f
    float* kv = qv + 147456;             // 147456 f
    float* vv = kv + 147456;             // 147456 f
    float* ao = vv + 147456;             // 147456 f
    ushort* kb = (ushort*)(ao + 147456); // 147456 u16  (total ~2.6 MB)

    hipLaunchKernelGGL(qkv_kernel, dim3(2304), dim3(192), 0, stream,
                       conv_w, qkv_w, qkv_b, qv, kv, vv);
    hipLaunchKernelGGL(attn_kernel, dim3(512), dim3(64), 0, stream, qv, kv, vv, ao);
    hipLaunchKernelGGL(proj_se_kernel, dim3(256), dim3(64), 0, stream,
                       ao, proj_w, proj_b, se_w1, se_b1, se_w2, se_b2, kb);
    hipLaunchKernelGGL(conv_kernel, dim3(8, 8, 32), dim3(256), 0, stream, x, kb, out);
}

// Round 3
// 123.499 us; speedup vs baseline: 1.4301x; 1.3773x over previous
//
#include <hip/hip_runtime.h>
#include <hip/hip_bf16.h>

typedef __bf16 bf16x8 __attribute__((ext_vector_type(8)));
typedef float  f32x4  __attribute__((ext_vector_type(4)));

// ---------------------------------------------------------------------------
// Stage 1: qkv = kern_tok @ qkv_w + qkv_b ; split into q(scaled),k,v
// ---------------------------------------------------------------------------
__global__ __launch_bounds__(192) void qkv_kernel(
    const float* __restrict__ conv_w, const float* __restrict__ qkv_w,
    const float* __restrict__ qkv_b,
    float* __restrict__ qv, float* __restrict__ kvv, float* __restrict__ vv)
{
    __shared__ float tok[64];
    const int bid = blockIdx.x;          // co*36 + s
    const int co = bid / 36, s = bid - co * 36;
    const int w = s / 9, p = s - w * 9;
    const int t = threadIdx.x;           // 192
    if (t < 64) tok[t] = conv_w[(((w * 64 + co) * 64 + t) * 9) + p];
    __syncthreads();
    float acc = qkv_b[t];
#pragma unroll 8
    for (int ci = 0; ci < 64; ++ci) acc += tok[ci] * qkv_w[ci * 192 + t];
    const int trip = t >> 6, rem = t & 63, h = rem >> 3, d = rem & 7;
    if (trip == 0) acc *= 0.35355339059327373f;   // hd^-0.5, hd=8
    float* dst = (trip == 0) ? qv : ((trip == 1) ? kvv : vv);
    dst[((co * 8 + h) * 36 + s) * 8 + d] = acc;
}

// ---------------------------------------------------------------------------
// Stage 2: attention per (co, head): softmax(q k^T) v  -> ao[co][s][h*8+d]
// ---------------------------------------------------------------------------
__global__ __launch_bounds__(64) void attn_kernel(
    const float* __restrict__ qv, const float* __restrict__ kvv,
    const float* __restrict__ vv, float* __restrict__ ao)
{
    __shared__ float kl[288], vl[288];
    const int bid = blockIdx.x;          // co*8 + h
    const int t = threadIdx.x;           // 64
    const float* kb = kvv + bid * 288;
    const float* vb = vv + bid * 288;
    for (int i = t; i < 288; i += 64) { kl[i] = kb[i]; vl[i] = vb[i]; }
    __syncthreads();
    if (t < 36) {
        float q[8];
        const float* qb = qv + bid * 288 + t * 8;
#pragma unroll
        for (int d = 0; d < 8; ++d) q[d] = qb[d];
        float sc[36];
        float mx = -1e30f;
#pragma unroll
        for (int u = 0; u < 36; ++u) {
            float a = 0.f;
#pragma unroll
            for (int d = 0; d < 8; ++d) a += q[d] * kl[u * 8 + d];
            sc[u] = a;
            mx = fmaxf(mx, a);
        }
        float sum = 0.f;
        float o[8] = {0.f,0.f,0.f,0.f,0.f,0.f,0.f,0.f};
#pragma unroll
        for (int u = 0; u < 36; ++u) {
            float e = expf(sc[u] - mx);
            sum += e;
#pragma unroll
            for (int d = 0; d < 8; ++d) o[d] += e * vl[u * 8 + d];
        }
        const float inv = 1.0f / sum;
        const int co = bid >> 3, h = bid & 7;
        float* dst = ao + (co * 36 + t) * 64 + h * 8;
#pragma unroll
        for (int d = 0; d < 8; ++d) dst[d] = o[d] * inv;
    }
}

// ---------------------------------------------------------------------------
// Stage 3: proj + SE + write bf16 kernels.
// kout layout: [((h*4 + w)*9 + p)][co][ci32]  (4 KB chunks; for fixed (h,w)
// taps p..p+1 are CONTIGUOUS 8 KB -> conv stages 2 taps per global_load_lds
// round).
// ---------------------------------------------------------------------------
__global__ __launch_bounds__(64) void proj_se_kernel(
    const float* __restrict__ ao, const float* __restrict__ proj_w,
    const float* __restrict__ proj_b,
    const float* __restrict__ se_w1, const float* __restrict__ se_b1,
    const float* __restrict__ se_w2, const float* __restrict__ se_b2,
    ushort* __restrict__ kout)
{
    __shared__ float al[9][64];
    __shared__ float pool[64];
    __shared__ float hb[4];
    const int bid = blockIdx.x;          // w*64 + co
    const int w = bid >> 6, co = bid & 63;
    const int t = threadIdx.x;           // 64 (= ci)
    for (int i = t; i < 576; i += 64) {
        int p = i >> 6, j = i & 63;
        al[p][j] = ao[(co * 36 + w * 9 + p) * 64 + j];
    }
    __syncthreads();
    float kv[9];
#pragma unroll
    for (int p = 0; p < 9; ++p) {
        float a = proj_b[t];
#pragma unroll 8
        for (int j = 0; j < 64; ++j) a += al[p][j] * proj_w[j * 64 + t];
        kv[p] = a;
    }
    float pl = 0.f;
#pragma unroll
    for (int p = 0; p < 9; ++p) pl += kv[p];
    pool[t] = pl * (1.0f / 9.0f);
    __syncthreads();
    if (t < 4) {
        float hh = se_b1[w * 4 + t];
#pragma unroll 8
        for (int c = 0; c < 64; ++c) hh += pool[c] * se_w1[(w * 4 + t) * 64 + c];
        hb[t] = fmaxf(hh, 0.0f);
    }
    __syncthreads();
    float z = se_b2[w * 64 + t];
#pragma unroll
    for (int d = 0; d < 4; ++d) z += hb[d] * se_w2[(w * 64 + t) * 4 + d];
    const float sg = 1.0f / (1.0f + expf(-z));
    const int hhalf = t >> 5, ci32 = t & 31;
#pragma unroll
    for (int p = 0; p < 9; ++p) {
        __hip_bfloat16 hv = __float2bfloat16(kv[p] * sg);
        kout[(((hhalf * 4 + w) * 9) + p) * 2048 + co * 32 + ci32] = *(const ushort*)&hv;
    }
}

// ---------------------------------------------------------------------------
// Stage 4: dynamic per-window 3x3 conv, implicit GEMM, bf16 MFMA.
// Tile 16x16 px, N=64 co, K = 2 ci-halves x 9 taps, 10 stages of <=2 taps.
//
// Round-3 changes (L2-thrash + barrier-cadence attack):
//  - XCD-chunked block remap (bijective, 2048%8==0): each XCD owns 4
//    complete (w,b) images of contiguous tiles -> halo rows + the window's
//    72 KB kern stay hot in that XCD's private L2.
//  - Non-temporal epilogue stores: out lines are never re-read; stop
//    write-allocating them in L2 (round-2 WRITE_SIZE was 1.8x ideal from
//    partial-line eviction). Frees ~40% of L2 for x.
//  - 2-tap kern stages: 10 stages (32 MFMA/barrier) instead of 18; kern
//    dbuf 2x8 KB via global_load_lds issued one stage ahead.
//  - Staging loads unconditional (clamped addr + cndmask zero) so all 11
//    float4 loads per thread issue back-to-back (no exec-mask serialization).
//  - LDS 37120 B -> 4 blocks/CU with __launch_bounds__(256,4).
// ---------------------------------------------------------------------------
__global__ __launch_bounds__(256, 4) void conv_kernel(
    const float* __restrict__ x, const ushort* __restrict__ kern,
    float* __restrict__ out)
{
    __shared__ alignas(16) ushort in_lds[18 * 18 * 32];   // 20736 B
    __shared__ alignas(16) ushort kn_lds[2 * 4096];       // 16384 B (2 x 8KB)

    const int tid = threadIdx.x;

    // ---- XCD-chunked bijective remap: XCD k processes nb in [k*256,(k+1)*256)
    const int bid = blockIdx.x;                 // 0..2047, xcd = bid & 7
    const int nb  = ((bid & 7) << 8) + (bid >> 3);
    const int bz  = nb >> 6;                    // (w*8+b), 4 per XCD
    const int rem = nb & 63;
    const int i0  = (rem >> 3) << 4;
    const int j0  = (rem & 7) << 4;
    const int w = bz >> 3, b = bz & 7;
    const int gi = w >> 1, gj = w & 1;

    const int wv   = tid >> 6;
    const int lane = tid & 63;
    const int l15  = lane & 15;
    const int hi4  = lane >> 4;        // 0..3

    // ---- async kern stage for stage sg (h = sg/5, taps 2*(sg%5)..):
    // chunk = ntap*4096 B contiguous at kern_b + (((h*4+w)*9)+2*(sg%5))*4096.
    const char* kern_b = (const char*)kern;
    auto stage_kern = [&](int sg, int buf) {
        const int h = sg / 5, j = sg % 5;
        const int ntap = (j == 4) ? 1 : 2;
        const char* gs = kern_b + (size_t)((((h * 4 + w) * 9) + 2 * j) << 12);
        char* ld = (char*)kn_lds + (buf << 13);
        if (ntap == 2) {
            const int o = wv << 11;
            __builtin_amdgcn_global_load_lds(
                (const __attribute__((address_space(1))) unsigned int*)(gs + o + (lane << 4)),
                (__attribute__((address_space(3))) unsigned int*)(ld + o), 16, 0, 0);
            __builtin_amdgcn_global_load_lds(
                (const __attribute__((address_space(1))) unsigned int*)(gs + o + 1024 + (lane << 4)),
                (__attribute__((address_space(3))) unsigned int*)(ld + o + 1024), 16, 0, 0);
        } else {
            const int o = wv << 10;
            __builtin_amdgcn_global_load_lds(
                (const __attribute__((address_space(1))) unsigned int*)(gs + o + (lane << 4)),
                (__attribute__((address_space(3))) unsigned int*)(ld + o), 16, 0, 0);
        }
    };

    // ---- input staging, one ci-half: 18x18 px, 32 ch, fp32->bf16.
    // 8 thr/px; 11 UNCONDITIONAL clamped loads, then cndmask-zero + cvt + write.
    auto stage_input = [&](int h) {
        const int cc = (tid & 7) << 2;     // channel-in-half 0..28
        const int p0 = tid >> 3;           // 0..31
        float4 v[11];
        unsigned okm = 0;
#pragma unroll
        for (int k = 0; k < 11; ++k) {
            const int pp = p0 + (k << 5);              // <= 351
            const int ppc = pp < 323 ? pp : 323;
            const int r = ppc / 18, q = ppc - r * 18;
            const int iy = i0 - 1 + r, jx = j0 - 1 + q;
            const bool ok = (pp < 324) & (iy >= 0) & (iy < 128) & (jx >= 0) & (jx < 128);
            const int iyc = iy < 0 ? 0 : (iy > 127 ? 127 : iy);
            const int jxc = jx < 0 ? 0 : (jx > 127 ? 127 : jx);
            const size_t xi = (((size_t)b << 16) +
                               (size_t)(gi * 128 + iyc) * 256 + (size_t)(gj * 128 + jxc)) * 64 +
                              h * 32 + cc;
            v[k] = *(const float4*)(x + xi);
            okm |= (unsigned)ok << k;
        }
#pragma unroll
        for (int k = 0; k < 11; ++k) {
            const int pp = p0 + (k << 5);
            if (pp < 324) {
                float4 z = (okm >> k) & 1 ? v[k] : make_float4(0.f, 0.f, 0.f, 0.f);
                union { ushort4 u; ushort h4[4]; } tmp;
                __hip_bfloat16 b0 = __float2bfloat16(z.x); tmp.h4[0] = *(const ushort*)&b0;
                __hip_bfloat16 b1 = __float2bfloat16(z.y); tmp.h4[1] = *(const ushort*)&b1;
                __hip_bfloat16 b2 = __float2bfloat16(z.z); tmp.h4[2] = *(const ushort*)&b2;
                __hip_bfloat16 b3 = __float2bfloat16(z.w); tmp.h4[3] = *(const ushort*)&b3;
                *(ushort4*)((char*)in_lds + ((pp << 6) + (cc << 1))) = tmp.u;
            }
        }
    };

    f32x4 acc[4][4];
#pragma unroll
    for (int mf = 0; mf < 4; ++mf)
#pragma unroll
        for (int nf = 0; nf < 4; ++nf)
            acc[mf][nf] = (f32x4){0.f, 0.f, 0.f, 0.f};

    // ---- prologue: kern stage 0 async + input half 0, one barrier
    stage_kern(0, 0);
    stage_input(0);
    __syncthreads();

#pragma unroll
    for (int sg = 0; sg < 10; ++sg) {
        const int buf = sg & 1;
        if (sg < 9) stage_kern(sg + 1, buf ^ 1);

        const int jj = sg % 5;
        const int ntap = (jj == 4) ? 1 : 2;
#pragma unroll
        for (int tt = 0; tt < 2; ++tt) {
            if (tt >= ntap) break;
            const int p = 2 * jj + tt;
            const int kh = p / 3, kw = p - kh * 3;

            bf16x8 Kf[4];
#pragma unroll
            for (int nf = 0; nf < 4; ++nf)
                Kf[nf] = *(const bf16x8*)((const char*)kn_lds +
                          ((buf << 13) + (tt << 12) + ((nf * 16 + l15) << 6) + (hi4 << 4)));

            const int q = l15 + kw;
#pragma unroll
            for (int mf = 0; mf < 4; ++mf) {
                const int r = wv * 4 + mf + kh;
                bf16x8 Af = *(const bf16x8*)((const char*)in_lds +
                              (((r * 18 + q) << 6) + (hi4 << 4)));
#pragma unroll
                for (int nf = 0; nf < 4; ++nf)
                    acc[mf][nf] = __builtin_amdgcn_mfma_f32_16x16x32_bf16(
                        Kf[nf], Af, acc[mf][nf], 0, 0, 0);
            }
        }

        if (sg == 4) {
            // all waves done with half-0 input; restage with half 1
            __syncthreads();
            stage_input(1);
        }
        __syncthreads();
    }

    // ---- epilogue: D col(l15)=px j, row(hi4*4+reg)=co (4 consecutive co).
    // Non-temporal f32x4 stores: out is never re-read, don't allocate in L2.
#pragma unroll
    for (int mf = 0; mf < 4; ++mf) {
        const int iloc = wv * 4 + mf;
        const size_t rowoff = ((size_t)b << 16) +
                              (size_t)(gi * 128 + i0 + iloc) * 256 + (size_t)(gj * 128 + j0);
#pragma unroll
        for (int nf = 0; nf < 4; ++nf) {
            f32x4* dst = (f32x4*)(out + (rowoff + l15) * 64 + nf * 16 + hi4 * 4);
            __builtin_nontemporal_store(acc[mf][nf], dst);
        }
    }
}

// ---------------------------------------------------------------------------
extern "C" void kernel_launch(void* const* d_in, const int* in_sizes, int n_in,
                              void* d_out, int out_size, void* d_ws, size_t ws_size,
                              hipStream_t stream)
{
    const float* x      = (const float*)d_in[0];
    const float* conv_w = (const float*)d_in[1];
    const float* qkv_w  = (const float*)d_in[2];
    const float* qkv_b  = (const float*)d_in[3];
    const float* proj_w = (const float*)d_in[4];
    const float* proj_b = (const float*)d_in[5];
    const float* se_w1  = (const float*)d_in[6];
    const float* se_b1  = (const float*)d_in[7];
    const float* se_w2  = (const float*)d_in[8];
    const float* se_b2  = (const float*)d_in[9];
    float* out = (float*)d_out;

    float* qv = (float*)d_ws;            // 147456 f
    float* kv = qv + 147456;             // 147456 f
    float* vv = kv + 147456;             // 147456 f
    float* ao = vv + 147456;             // 147456 f
    ushort* kb = (ushort*)(ao + 147456); // 147456 u16  (total ~2.6 MB)

    hipLaunchKernelGGL(qkv_kernel, dim3(2304), dim3(192), 0, stream,
                       conv_w, qkv_w, qkv_b, qv, kv, vv);
    hipLaunchKernelGGL(attn_kernel, dim3(512), dim3(64), 0, stream, qv, kv, vv, ao);
    hipLaunchKernelGGL(proj_se_kernel, dim3(256), dim3(64), 0, stream,
                       ao, proj_w, proj_b, se_w1, se_b1, se_w2, se_b2, kb);
    hipLaunchKernelGGL(conv_kernel, dim3(2048), dim3(256), 0, stream, x, kb, out);
}